// Round 10
// baseline (1867.807 us; speedup 1.0000x reference)
//
#include <hip/hip_runtime.h>
#include <math.h>

#define T_LEN 3000
#define HID 64

typedef _Float16 f16;
typedef f16 h2 __attribute__((ext_vector_type(2)));

__device__ __forceinline__ float sigmoid_f(float v) {
    return __builtin_amdgcn_rcpf(1.0f + __expf(-v));
}
__device__ __forceinline__ float tanh_f(float v) {
    return fmaf(2.0f, __builtin_amdgcn_rcpf(1.0f + __expf(-2.0f * v)), -1.0f);
}

// R10: two independent GRU chains per wave (batch elements 2b, 2b+1).
// R6 post-mortem: single chain is latency-bound (786 cyc/step vs ~230 issue)
// -- the h LDS write->read round trip (~240 cyc) and transcendental tail
// (~80 cyc) have nothing to overlap them. R9 showed multi-wave barriers cost
// ~650 cyc/step -> dead end. Here chain B's dot2 issue hides chain A's
// latency and vice versa; weights are shared (one 96-VGPR f16 set), only
// accumulators/h/LDS buffers duplicate. Per-step (both chains) ~550 cyc
// issue-bound.
__global__
__attribute__((amdgpu_flat_work_group_size(64, 64), amdgpu_waves_per_eu(1, 1)))
void gru_e2(
    const float* __restrict__ x,     // (B, T, 1)
    const float* __restrict__ W_ih,  // (192, 1)
    const float* __restrict__ W_hh,  // (192, 64)
    const float* __restrict__ b_ih,  // (192,)
    const float* __restrict__ b_hh,  // (192,)
    const float* __restrict__ W_fc,  // (1, 64)
    const float* __restrict__ b_fc,  // (1,)
    float* __restrict__ out)         // (B,)
{
    const int bA = 2 * blockIdx.x;
    const int bB = bA + 1;
    const int g  = threadIdx.x;  // 0..63, hidden unit index
    const long xbaseA = (long)bA * T_LEN;
    const long xbaseB = (long)bB * T_LEN;

    __shared__ __align__(16) f16 hA_lds[HID];   // 128 B each
    __shared__ __align__(16) f16 hB_lds[HID];
    __shared__ float xA_lds[64];
    __shared__ float xB_lds[64];

    // ---- one-time: W_hh rows for unit g -> f16 pairs (96 VGPRs, shared) ----
    h2 wr[32], wz[32], wn[32];
    {
        const float4* Wr4 = reinterpret_cast<const float4*>(W_hh + (size_t)(g)       * HID);
        const float4* Wz4 = reinterpret_cast<const float4*>(W_hh + (size_t)(64 + g)  * HID);
        const float4* Wn4 = reinterpret_cast<const float4*>(W_hh + (size_t)(128 + g) * HID);
#pragma unroll
        for (int i = 0; i < 16; ++i) {
            float4 a = Wr4[i];
            h2 t0; t0.x = (f16)a.x; t0.y = (f16)a.y; wr[2*i]   = t0;
            h2 t1; t1.x = (f16)a.z; t1.y = (f16)a.w; wr[2*i+1] = t1;
            float4 c = Wz4[i];
            h2 t2; t2.x = (f16)c.x; t2.y = (f16)c.y; wz[2*i]   = t2;
            h2 t3; t3.x = (f16)c.z; t3.y = (f16)c.w; wz[2*i+1] = t3;
            float4 d = Wn4[i];
            h2 t4; t4.x = (f16)d.x; t4.y = (f16)d.y; wn[2*i]   = t4;
            h2 t5; t5.x = (f16)d.z; t5.y = (f16)d.w; wn[2*i+1] = t5;
        }
    }
#pragma unroll
    for (int i = 0; i < 32; ++i) {
        asm volatile("" : "+v"(wr[i]), "+v"(wz[i]), "+v"(wn[i]));
    }

    const float wihr = W_ih[g],        wihz = W_ih[64 + g],   wihn = W_ih[128 + g];
    const float br   = b_ih[g]      + b_hh[g];
    const float bz   = b_ih[64 + g] + b_hh[64 + g];
    const float bin  = b_ih[128 + g];
    const float bhn  = b_hh[128 + g];

    // init h and first x chunks (single wave: DS in-order, no barrier needed)
    hA_lds[g] = (f16)0.0f;
    hB_lds[g] = (f16)0.0f;
    xA_lds[g] = x[xbaseA + g];
    xB_lds[g] = x[xbaseB + g];
    float xnA = (64 + g < T_LEN) ? x[xbaseA + 64 + g] : 0.0f;
    float xnB = (64 + g < T_LEN) ? x[xbaseB + 64 + g] : 0.0f;
    float hA = 0.0f, hB = 0.0f;  // lane g holds h[g] of each chain in fp32
    __builtin_amdgcn_wave_barrier();

    const float4* hA4 = reinterpret_cast<const float4*>(hA_lds);
    const float4* hB4 = reinterpret_cast<const float4*>(hB_lds);

    for (int t = 0; t < T_LEN; ++t) {
        const int j = t & 63;

        // ---- both chains' matvecs, interleaved (independent -> overlap) ----
        float arA0 = 0.f, arA1 = 0.f, azA0 = 0.f, azA1 = 0.f, anA0 = 0.f, anA1 = 0.f;
        float arB0 = 0.f, arB1 = 0.f, azB0 = 0.f, azB1 = 0.f, anB0 = 0.f, anB1 = 0.f;
#pragma unroll
        for (int i = 0; i < 8; ++i) {
            union { float4 f; h2 h[4]; } uA, uB;
            uA.f = hA4[i];
            uB.f = hB4[i];
            arA0 = __builtin_amdgcn_fdot2(wr[4*i+0], uA.h[0], arA0, false);
            arB0 = __builtin_amdgcn_fdot2(wr[4*i+0], uB.h[0], arB0, false);
            azA0 = __builtin_amdgcn_fdot2(wz[4*i+0], uA.h[0], azA0, false);
            azB0 = __builtin_amdgcn_fdot2(wz[4*i+0], uB.h[0], azB0, false);
            anA0 = __builtin_amdgcn_fdot2(wn[4*i+0], uA.h[0], anA0, false);
            anB0 = __builtin_amdgcn_fdot2(wn[4*i+0], uB.h[0], anB0, false);
            arA0 = __builtin_amdgcn_fdot2(wr[4*i+1], uA.h[1], arA0, false);
            arB0 = __builtin_amdgcn_fdot2(wr[4*i+1], uB.h[1], arB0, false);
            azA0 = __builtin_amdgcn_fdot2(wz[4*i+1], uA.h[1], azA0, false);
            azB0 = __builtin_amdgcn_fdot2(wz[4*i+1], uB.h[1], azB0, false);
            anA0 = __builtin_amdgcn_fdot2(wn[4*i+1], uA.h[1], anA0, false);
            anB0 = __builtin_amdgcn_fdot2(wn[4*i+1], uB.h[1], anB0, false);
            arA1 = __builtin_amdgcn_fdot2(wr[4*i+2], uA.h[2], arA1, false);
            arB1 = __builtin_amdgcn_fdot2(wr[4*i+2], uB.h[2], arB1, false);
            azA1 = __builtin_amdgcn_fdot2(wz[4*i+2], uA.h[2], azA1, false);
            azB1 = __builtin_amdgcn_fdot2(wz[4*i+2], uB.h[2], azB1, false);
            anA1 = __builtin_amdgcn_fdot2(wn[4*i+2], uA.h[2], anA1, false);
            anB1 = __builtin_amdgcn_fdot2(wn[4*i+2], uB.h[2], anB1, false);
            arA1 = __builtin_amdgcn_fdot2(wr[4*i+3], uA.h[3], arA1, false);
            arB1 = __builtin_amdgcn_fdot2(wr[4*i+3], uB.h[3], arB1, false);
            azA1 = __builtin_amdgcn_fdot2(wz[4*i+3], uA.h[3], azA1, false);
            azB1 = __builtin_amdgcn_fdot2(wz[4*i+3], uB.h[3], azB1, false);
            anA1 = __builtin_amdgcn_fdot2(wn[4*i+3], uA.h[3], anA1, false);
            anB1 = __builtin_amdgcn_fdot2(wn[4*i+3], uB.h[3], anB1, false);
        }

        // ---- tail A, publish hA immediately (starts A's DS round trip) ----
        {
            const float ar = arA0 + arA1, az = azA0 + azA1, an = anA0 + anA1;
            const float xt = xA_lds[j];
            const float r = sigmoid_f(fmaf(xt, wihr, br) + ar);
            const float z = sigmoid_f(fmaf(xt, wihz, bz) + az);
            const float n = tanh_f(fmaf(xt, wihn, bin) + r * (an + bhn));
            hA = fmaf(z, hA - n, n);
            hA_lds[g] = (f16)hA;
        }
        // ---- tail B ----
        {
            const float ar = arB0 + arB1, az = azB0 + azB1, an = anB0 + anB1;
            const float xt = xB_lds[j];
            const float r = sigmoid_f(fmaf(xt, wihr, br) + ar);
            const float z = sigmoid_f(fmaf(xt, wihz, bz) + az);
            const float n = tanh_f(fmaf(xt, wihn, bin) + r * (an + bhn));
            hB = fmaf(z, hB - n, n);
            hB_lds[g] = (f16)hB;
        }

        if (j == 63) {
            __builtin_amdgcn_wave_barrier();
            xA_lds[g] = xnA;
            xB_lds[g] = xnB;
            const int idx = t + 65 + g;  // chunk after next
            xnA = (idx < T_LEN) ? x[xbaseA + idx] : 0.0f;
            xnB = (idx < T_LEN) ? x[xbaseB + idx] : 0.0f;
            __builtin_amdgcn_wave_barrier();
        }
    }

    // ---- epilogue: two dot-reductions ----
    const float wfc = W_fc[g];
    float vA = hA * wfc;
    float vB = hB * wfc;
#pragma unroll
    for (int off = 32; off > 0; off >>= 1) {
        vA += __shfl_down(vA, off);
        vB += __shfl_down(vB, off);
    }
    if (g == 0) {
        const float bias = b_fc[0];
        out[bA] = vA + bias;
        out[bB] = vB + bias;
    }
}

extern "C" void kernel_launch(void* const* d_in, const int* in_sizes, int n_in,
                              void* d_out, int out_size, void* d_ws, size_t ws_size,
                              hipStream_t stream) {
    const float* x    = (const float*)d_in[0];
    const float* W_ih = (const float*)d_in[1];
    const float* W_hh = (const float*)d_in[2];
    const float* b_ih = (const float*)d_in[3];
    const float* b_hh = (const float*)d_in[4];
    const float* W_fc = (const float*)d_in[5];
    const float* b_fc = (const float*)d_in[6];
    float* out = (float*)d_out;

    const int B = 256;  // in_sizes[0] = B*T = 768000 -> B=256, T=3000
    gru_e2<<<B / 2, 64, 0, stream>>>(x, W_ih, W_hh, b_ih, b_hh, W_fc, b_fc, out);
}